// Round 1
// baseline (749.391 us; speedup 1.0000x reference)
//
#include <hip/hip_runtime.h>
#include <stdint.h>

// Problem constants (from reference)
#define NPATHS 4096
#define LPATH  8
#define DIM    256     // input dim
#define HID    256     // hidden dim
#define KDIM   512     // DIM + HID
#define NGATE  1024    // 4*HID

typedef short  short4v __attribute__((ext_vector_type(4)));
typedef short  short8v __attribute__((ext_vector_type(8)));
typedef float  float4v __attribute__((ext_vector_type(4)));

__device__ __forceinline__ unsigned short f2bf(float f) {
    union { float f; uint32_t u; } v; v.f = f;
    uint32_t u = v.u;
    u += 0x7FFFu + ((u >> 16) & 1u);   // round-to-nearest-even
    return (unsigned short)(u >> 16);
}

__device__ __forceinline__ float fast_sigmoid(float x) {
    return 1.0f / (1.0f + __expf(-x));
}
__device__ __forceinline__ float fast_tanh(float x) {
    x = fminf(15.0f, fmaxf(-15.0f, x));
    float e = __expf(2.0f * x);
    return (e - 1.0f) / (e + 1.0f);
}

// ---------------------------------------------------------------------------
// K0: pack Wc[1024][512] bf16 = [w_ih | w_hh], and bias = b_ih + b_hh
// ---------------------------------------------------------------------------
__global__ void prep_kernel(const float* __restrict__ w_ih, const float* __restrict__ w_hh,
                            const float* __restrict__ b_ih, const float* __restrict__ b_hh,
                            unsigned short* __restrict__ Wc, float* __restrict__ bias) {
    int gid  = blockIdx.x * blockDim.x + threadIdx.x;   // 512*256 = 131072 threads
    int base = gid * 4;                                  // 4 elems each -> 524288 total
    int row  = base >> 9;                                // /512
    int col  = base & 511;
    const float* src = (col < DIM) ? (w_ih + row * DIM + col)
                                   : (w_hh + row * DIM + (col - DIM));
    float4 v = *(const float4*)src;                      // col%4==0, halves 256-aligned
    short4v pk = {(short)f2bf(v.x), (short)f2bf(v.y), (short)f2bf(v.z), (short)f2bf(v.w)};
    *(short4v*)(Wc + base) = pk;
    if (gid < NGATE) bias[gid] = b_ih[gid] + b_hh[gid];
}

// ---------------------------------------------------------------------------
// K1: persistent LSTM. 256 blocks x 256 threads; block owns 16 paths.
// Wave w computes gate columns { g*256 + w*64 + u*16 + lane15 : g,u in 0..3 }
// so i,f,g,o of a (path,unit) live in one lane -> register-only update.
// xh LDS row = [ x_t (256 bf16) | h (256 bf16) ], padded stride vs bank conflicts.
// ---------------------------------------------------------------------------
#define XH_STRIDE 520   // shorts per row: 512 + 8 pad (1040 B -> 2-way-free LDS banking)
#define C_STRIDE  260   // floats per row: 256 + 4 pad

__global__ __launch_bounds__(256, 1)
void lstm_kernel(const float* __restrict__ embedding,
                 const int*   __restrict__ paths,
                 const unsigned short* __restrict__ Wc,
                 const float* __restrict__ bias,
                 float* __restrict__ h_out,
                 float* __restrict__ logits) {
    __shared__ short xh[16 * XH_STRIDE];
    __shared__ float c_lds[16 * C_STRIDE];
    __shared__ float att_part[4 * 16];

    const int tid  = threadIdx.x;
    const int wave = tid >> 6;
    const int lane = tid & 63;
    const int l15  = lane & 15;
    const int quad = lane >> 4;
    const int p0   = blockIdx.x * 16;

    // zero-init c and h(part of xh)
    for (int i = tid; i < 16 * C_STRIDE; i += 256) c_lds[i] = 0.0f;
    for (int i = tid; i < 16 * 256; i += 256) {
        int r = i >> 8, k = i & 255;
        xh[r * XH_STRIDE + 256 + k] = 0;
    }
    __syncthreads();

    // per-lane B base: row = wave*64 + l15 (within its col group), k-off = quad*8
    const unsigned short* bbase = Wc + (size_t)(wave * 64 + l15) * KDIM + quad * 8;

    float hmax[4] = {-1e30f, -1e30f, -1e30f, -1e30f};
    float4v acc[16];
    const float4v zero4 = {0.0f, 0.0f, 0.0f, 0.0f};

    for (int t = 0; t < LPATH; ++t) {
        // ---- gather x_t -> xh[:, 0:256] (bf16) ----
        {
            int r   = tid >> 4;
            int seg = tid & 15;
            int node = paths[(p0 + r) * LPATH + t];
            const float4* src = (const float4*)(embedding + (size_t)node * DIM) + seg * 4;
            short* dst = xh + r * XH_STRIDE + seg * 16;
#pragma unroll
            for (int j = 0; j < 4; ++j) {
                float4 v = src[j];
                short4v pk = {(short)f2bf(v.x), (short)f2bf(v.y),
                              (short)f2bf(v.z), (short)f2bf(v.w)};
                *(short4v*)(dst + j * 4) = pk;
            }
        }
        __syncthreads();

        // ---- GEMM: gates[16 rows][wave's 256 cols] = xh @ Wc^T ----
#pragma unroll
        for (int ct = 0; ct < 16; ++ct) acc[ct] = zero4;
#pragma unroll
        for (int kc = 0; kc < 16; ++kc) {
            short8v a = *(const short8v*)(xh + l15 * XH_STRIDE + kc * 32 + quad * 8);
#pragma unroll
            for (int g = 0; g < 4; ++g) {
#pragma unroll
                for (int u = 0; u < 4; ++u) {
                    short8v b = *(const short8v*)(bbase + (size_t)(g * 256 + u * 16) * KDIM + kc * 32);
                    acc[g * 4 + u] =
                        __builtin_amdgcn_mfma_f32_16x16x32_bf16(a, b, acc[g * 4 + u], 0, 0, 0);
                }
            }
        }
        __syncthreads();   // all waves done reading xh before h is overwritten

        // ---- pointwise LSTM update (register-local: i,f,g,o in same lane) ----
#pragma unroll
        for (int u = 0; u < 4; ++u) {
            int q = wave * 64 + u * 16 + l15;          // hidden unit 0..255
            float bi = bias[0 * HID + q];
            float bf = bias[1 * HID + q];
            float bg = bias[2 * HID + q];
            float bo = bias[3 * HID + q];
#pragma unroll
            for (int r = 0; r < 4; ++r) {
                int row = quad * 4 + r;                // path row 0..15 (C/D layout)
                float iv = acc[0 * 4 + u][r] + bi;
                float fv = acc[1 * 4 + u][r] + bf;
                float gv = acc[2 * 4 + u][r] + bg;
                float ov = acc[3 * 4 + u][r] + bo;
                float c_old = c_lds[row * C_STRIDE + q];
                float c_new = fast_sigmoid(fv) * c_old + fast_sigmoid(iv) * fast_tanh(gv);
                c_lds[row * C_STRIDE + q] = c_new;
                float h = fast_sigmoid(ov) * fast_tanh(c_new);
                xh[row * XH_STRIDE + 256 + q] = (short)f2bf(h);
                if (t == LPATH - 1) {
                    h_out[(size_t)(p0 + row) * HID + q] = h;
                    hmax[r] = fmaxf(hmax[r], h);
                }
            }
        }
        // next iteration's gather writes xh[:,0:256] (disjoint from h region);
        // the post-gather __syncthreads joins this update before GEMM reads h.
    }

    // ---- attention logit: max over hidden per path ----
#pragma unroll
    for (int r = 0; r < 4; ++r) {
        float m = hmax[r];
        m = fmaxf(m, __shfl_xor(m, 1, 64));
        m = fmaxf(m, __shfl_xor(m, 2, 64));
        m = fmaxf(m, __shfl_xor(m, 4, 64));
        m = fmaxf(m, __shfl_xor(m, 8, 64));
        if (l15 == 0) att_part[wave * 16 + quad * 4 + r] = m;
    }
    __syncthreads();
    if (tid < 16) {
        float m = fmaxf(fmaxf(att_part[0 * 16 + tid], att_part[1 * 16 + tid]),
                        fmaxf(att_part[2 * 16 + tid], att_part[3 * 16 + tid]));
        logits[p0 + tid] = m;
    }
}

// ---------------------------------------------------------------------------
// K2: softmax prep over 4096 logits (max, 1/Z) + zero path_emb accumulator
// ---------------------------------------------------------------------------
__global__ void softmax_prep_kernel(const float* __restrict__ logits,
                                    float* __restrict__ scal,
                                    float* __restrict__ path_emb) {
    __shared__ float red[256];
    int tid = threadIdx.x;
    float m = -1e30f;
    for (int i = tid; i < NPATHS; i += 256) m = fmaxf(m, logits[i]);
    red[tid] = m; __syncthreads();
    for (int s = 128; s > 0; s >>= 1) {
        if (tid < s) red[tid] = fmaxf(red[tid], red[tid + s]);
        __syncthreads();
    }
    float bmax = red[0];
    __syncthreads();
    float sum = 0.0f;
    for (int i = tid; i < NPATHS; i += 256) sum += __expf(logits[i] - bmax);
    red[tid] = sum; __syncthreads();
    for (int s = 128; s > 0; s >>= 1) {
        if (tid < s) red[tid] += red[tid + s];
        __syncthreads();
    }
    if (tid == 0) { scal[0] = bmax; scal[1] = 1.0f / red[0]; }
    path_emb[tid] = 0.0f;
}

// ---------------------------------------------------------------------------
// K3: path_emb[t] = sum_p softmax_p * h_out[p][t]  (block partial + atomic)
// ---------------------------------------------------------------------------
__global__ void attn_sum_kernel(const float* __restrict__ h_out,
                                const float* __restrict__ logits,
                                const float* __restrict__ scal,
                                float* __restrict__ path_emb) {
    int tid = threadIdx.x;
    int p0  = blockIdx.x * 16;
    float bmax = scal[0], invZ = scal[1];
    float acc = 0.0f;
    for (int p = p0; p < p0 + 16; ++p) {
        float w = __expf(logits[p] - bmax) * invZ;
        acc += w * h_out[(size_t)p * HID + tid];
    }
    atomicAdd(&path_emb[tid], acc);
}

// ---------------------------------------------------------------------------
// K4: out = sigmoid([user|item|path_emb] . w_lin + b_lin)
// ---------------------------------------------------------------------------
__global__ void final_kernel(const float* __restrict__ embedding,
                             const int* __restrict__ user_id,
                             const int* __restrict__ item_id,
                             const float* __restrict__ w_lin,
                             const float* __restrict__ b_lin,
                             const float* __restrict__ path_emb,
                             float* __restrict__ out) {
    __shared__ float red[256];
    int tid = threadIdx.x;
    int u  = user_id[0];
    int it = item_id[0];
    float s = w_lin[tid]       * embedding[(size_t)u  * DIM + tid]
            + w_lin[256 + tid] * embedding[(size_t)it * DIM + tid]
            + w_lin[512 + tid] * path_emb[tid];
    red[tid] = s; __syncthreads();
    for (int st = 128; st > 0; st >>= 1) {
        if (tid < st) red[tid] += red[tid + st];
        __syncthreads();
    }
    if (tid == 0) out[0] = 1.0f / (1.0f + __expf(-(red[0] + b_lin[0])));
}

// ---------------------------------------------------------------------------
extern "C" void kernel_launch(void* const* d_in, const int* in_sizes, int n_in,
                              void* d_out, int out_size, void* d_ws, size_t ws_size,
                              hipStream_t stream) {
    const float* embedding = (const float*)d_in[0];
    const float* w_ih      = (const float*)d_in[1];
    const float* w_hh      = (const float*)d_in[2];
    const float* b_ih      = (const float*)d_in[3];
    const float* b_hh      = (const float*)d_in[4];
    const float* w_lin     = (const float*)d_in[5];
    const float* b_lin     = (const float*)d_in[6];
    const int*   paths     = (const int*)d_in[7];
    const int*   user_id   = (const int*)d_in[8];
    const int*   item_id   = (const int*)d_in[9];
    float* outp = (float*)d_out;

    // workspace layout (~5.3 MB)
    char* ws = (char*)d_ws;
    unsigned short* Wc    = (unsigned short*)ws;                       // 1 MB
    float* bias           = (float*)(ws + (1 << 20));                  // 4 KB
    float* h_out          = (float*)(ws + (1 << 20) + 4096);           // 4 MB
    float* logits         = (float*)(ws + (1 << 20) + 4096 + (4 << 20));       // 16 KB
    float* scal           = (float*)(ws + (1 << 20) + 4096 + (4 << 20) + 16384); // 2 floats
    float* path_emb       = scal + 4;                                  // 1 KB

    prep_kernel<<<512, 256, 0, stream>>>(w_ih, w_hh, b_ih, b_hh, Wc, bias);
    lstm_kernel<<<256, 256, 0, stream>>>(embedding, paths, Wc, bias, h_out, logits);
    softmax_prep_kernel<<<1, 256, 0, stream>>>(logits, scal, path_emb);
    attn_sum_kernel<<<NPATHS / 16, 256, 0, stream>>>(h_out, logits, scal, path_emb);
    final_kernel<<<1, 256, 0, stream>>>(embedding, user_id, item_id, w_lin, b_lin, path_emb, outp);
}

// Round 2
// 283.681 us; speedup vs baseline: 2.6417x; 2.6417x over previous
//
#include <hip/hip_runtime.h>
#include <stdint.h>

#define NPATHS 4096
#define LPATH  8
#define DIM    256
#define HID    256
#define KDIM   512
#define NGATE  1024

typedef short  short4v __attribute__((ext_vector_type(4)));
typedef short  short8v __attribute__((ext_vector_type(8)));
typedef float  float4v __attribute__((ext_vector_type(4)));

__device__ __forceinline__ unsigned short f2bf(float f) {
    union { float f; uint32_t u; } v; v.f = f;
    uint32_t u = v.u;
    u += 0x7FFFu + ((u >> 16) & 1u);   // round-to-nearest-even
    return (unsigned short)(u >> 16);
}

__device__ __forceinline__ float fast_sigmoid(float x) {
    return 1.0f / (1.0f + __expf(-x));
}
__device__ __forceinline__ float fast_tanh(float x) {
    x = fminf(15.0f, fmaxf(-15.0f, x));
    float e = __expf(2.0f * x);
    return (e - 1.0f) / (e + 1.0f);
}

// monotone float->uint encoding for atomicMax over signed floats
__device__ __forceinline__ unsigned int encf(float f) {
    unsigned int u = __float_as_uint(f);
    return (u & 0x80000000u) ? ~u : (u | 0x80000000u);
}

// async global->LDS DMA, 16 B per lane (global_load_lds_dwordx4).
// LDS dest must be wave-uniform base + lane*16 (we pass per-lane ptr matching).
__device__ __forceinline__ void dma16(void* lds, const void* g) {
    typedef const unsigned int __attribute__((address_space(1)))* gp_t;
    typedef unsigned int __attribute__((address_space(3)))* lp_t;
    gp_t gp = reinterpret_cast<gp_t>(reinterpret_cast<uintptr_t>(g));
    lp_t lp = reinterpret_cast<lp_t>(static_cast<unsigned int>(reinterpret_cast<uintptr_t>(lds)));
    __builtin_amdgcn_global_load_lds(gp, lp, 16, 0, 0);
}

// ---------------------------------------------------------------------------
// K0: pack Wc[1024][512] bf16 = [w_ih | w_hh], bias = b_ih + b_hh,
//     zero-init encoded attention logits.
// ---------------------------------------------------------------------------
__global__ void prep_kernel(const float* __restrict__ w_ih, const float* __restrict__ w_hh,
                            const float* __restrict__ b_ih, const float* __restrict__ b_hh,
                            unsigned short* __restrict__ Wc, float* __restrict__ bias,
                            unsigned int* __restrict__ logits_enc) {
    int gid  = blockIdx.x * blockDim.x + threadIdx.x;   // 131072 threads
    int base = gid * 4;
    int row  = base >> 9;
    int col  = base & 511;
    const float* src = (col < DIM) ? (w_ih + row * DIM + col)
                                   : (w_hh + row * DIM + (col - DIM));
    float4 v = *(const float4*)src;
    short4v pk = {(short)f2bf(v.x), (short)f2bf(v.y), (short)f2bf(v.z), (short)f2bf(v.w)};
    *(short4v*)(Wc + base) = pk;
    if (gid < NGATE) bias[gid] = b_ih[gid] + b_hh[gid];
    if (gid < NPATHS) logits_enc[gid] = 0u;   // < encf(any real float)
}

// ---------------------------------------------------------------------------
// K1: gather + convert embeddings -> Xb[8][4096][256] bf16 (t-major planes)
// ---------------------------------------------------------------------------
__global__ void gather_kernel(const float* __restrict__ embedding,
                              const int* __restrict__ paths,
                              unsigned short* __restrict__ Xb) {
    int gid = blockIdx.x * 256 + threadIdx.x;   // 8192 blocks -> 2M threads
    int row = gid >> 6;                          // 0..32767  (= t*4096 + p)
    int seg = gid & 63;
    int p = row & (NPATHS - 1);
    int t = row >> 12;
    int node = paths[p * LPATH + t];
    float4 v = *(const float4*)(embedding + (size_t)node * DIM + seg * 4);
    short4v pk = {(short)f2bf(v.x), (short)f2bf(v.y), (short)f2bf(v.z), (short)f2bf(v.w)};
    *(short4v*)(Xb + (size_t)row * DIM + seg * 4) = pk;
}

// ---------------------------------------------------------------------------
// K2: one LSTM step as a 4096x1024 (K=512) MFMA GEMM + fused pointwise.
// Block = 128 paths x 128 gate-cols (4 gates x 32 units -> ut strip).
// grid = 32 path-tiles x 8 unit-tiles = 256 blocks, 256 threads.
// A rows = [x_t | h_{t-1}] bf16 (two global planes), staged by LDS-DMA.
// B rows = Wc rows {g*256 + ut*32 + 0..31}, staged by LDS-DMA.
// Double-buffered LDS, one barrier per K-iter; DMA for iter k+1 overlaps
// compute of iter k.  c[256 units][4096 paths] fp32 is block-private.
// ---------------------------------------------------------------------------
template<bool FIRST, bool LAST>
__global__ __launch_bounds__(256, 1)
void step_kernel(const unsigned short* __restrict__ Xb,     // [8][4096][256]
                 const unsigned short* __restrict__ Wc,     // [1024][512]
                 const float* __restrict__ bias,            // [1024]
                 const unsigned short* __restrict__ h_in,   // [4096][256] bf16
                 unsigned short* __restrict__ h_outp,       // [4096][256] bf16
                 float* __restrict__ c_g,                   // [256][4096] fp32
                 float* __restrict__ h_fin,                 // [256][4096] fp32 (LAST)
                 unsigned int* __restrict__ logits_enc,     // [4096]      (LAST)
                 int t) {
    __shared__ short sA[2][128 * 32];   // [buf][row 128][k 32]
    __shared__ short sB[2][128 * 32];
    __shared__ short hT[128 * 40];      // transpose buffer, 80-B rows (16B aligned)

    const int tid  = threadIdx.x;
    const int wave = tid >> 6;
    const int lane = tid & 63;
    const int l15  = lane & 15;
    const int quad = lane >> 4;
    const int pt = blockIdx.x >> 3;     // 0..31
    const int ut = blockIdx.x & 7;      // 0..7
    const int p0 = pt * 128;

    const int NITER = FIRST ? 8 : 16;   // FIRST: h=0, skip w_hh half

    const char* XbB = (const char*)Xb + (size_t)t * NPATHS * DIM * 2;
    const char* hB  = (const char*)h_in;
    const char* WcB = (const char*)Wc;

    // per-thread DMA assignment: 2 chunks of 16 B each for A and B
    const int fl0 = tid * 16, fl1 = 4096 + tid * 16;   // flat byte offset in 8 KB tile
    const int rA0 = fl0 >> 6, cb0 = fl0 & 63;          // LDS row (64 B rows), col byte
    const int rA1 = fl1 >> 6, cb1 = fl1 & 63;
    const int wr0 = ((rA0 >> 5) << 8) + ut * 32 + (rA0 & 31);  // Wc row for B
    const int wr1 = ((rA1 >> 5) << 8) + ut * 32 + (rA1 & 31);

    float4v acc[2][8];
    const float4v zero4 = {0.0f, 0.0f, 0.0f, 0.0f};
#pragma unroll
    for (int i = 0; i < 2; ++i)
#pragma unroll
        for (int j = 0; j < 8; ++j) acc[i][j] = zero4;

    auto issue = [&](int kc) {
        int buf = kc & 1;
        const char* abase = (kc < 8) ? XbB : hB;
        int ko = (kc & 7) * 64;                       // byte offset within 512-B row
        dma16(&sA[buf][fl0 >> 1], abase + (size_t)(p0 + rA0) * 512 + ko + cb0);
        dma16(&sA[buf][fl1 >> 1], abase + (size_t)(p0 + rA1) * 512 + ko + cb1);
        dma16(&sB[buf][fl0 >> 1], WcB + (size_t)wr0 * 1024 + kc * 64 + cb0);
        dma16(&sB[buf][fl1 >> 1], WcB + (size_t)wr1 * 1024 + kc * 64 + cb1);
    };

    issue(0);
    for (int kc = 0; kc < NITER; ++kc) {
        __syncthreads();                 // drains DMA(kc), joins compute(kc-1)
        if (kc + 1 < NITER) issue(kc + 1);
        int buf = kc & 1;
        const short* Ab = &sA[buf][(wave * 32 + l15) * 32 + quad * 8];
        short8v a0 = *(const short8v*)(Ab);
        short8v a1 = *(const short8v*)(Ab + 16 * 32);
#pragma unroll
        for (int ct = 0; ct < 8; ++ct) {
            short8v b = *(const short8v*)(&sB[buf][(ct * 16 + l15) * 32 + quad * 8]);
            acc[0][ct] = __builtin_amdgcn_mfma_f32_16x16x32_bf16(a0, b, acc[0][ct], 0, 0, 0);
            acc[1][ct] = __builtin_amdgcn_mfma_f32_16x16x32_bf16(a1, b, acc[1][ct], 0, 0, 0);
        }
    }

    // ---- pointwise LSTM update ----
    float pmax[8];
#pragma unroll
    for (int j = 0; j < 8; ++j) pmax[j] = -1e30f;

#pragma unroll
    for (int rt = 0; rt < 2; ++rt) {
#pragma unroll
        for (int uh = 0; uh < 2; ++uh) {
            int u  = ut * 32 + uh * 16 + l15;          // unit 0..255
            float bi = bias[0 * HID + u];
            float bfv = bias[1 * HID + u];
            float bg = bias[2 * HID + u];
            float bo = bias[3 * HID + u];
            int prow = wave * 32 + rt * 16 + quad * 4; // block-local path of reg 0
            float* cptr = c_g + (size_t)u * NPATHS + p0 + prow;
            float4 cold;
            if (!FIRST) cold = *(const float4*)cptr;
            float4 cnew, hv;
#pragma unroll
            for (int r = 0; r < 4; ++r) {
                float iv = acc[rt][0 * 2 + uh][r] + bi;
                float fv = acc[rt][1 * 2 + uh][r] + bfv;
                float gv = acc[rt][2 * 2 + uh][r] + bg;
                float ov = acc[rt][3 * 2 + uh][r] + bo;
                float cp = FIRST ? 0.0f : (&cold.x)[r];
                float cn = fast_sigmoid(fv) * cp + fast_sigmoid(iv) * fast_tanh(gv);
                (&cnew.x)[r] = cn;
                float h = fast_sigmoid(ov) * fast_tanh(cn);
                (&hv.x)[r] = h;
                pmax[rt * 4 + r] = fmaxf(pmax[rt * 4 + r], h);
            }
            *(float4*)cptr = cnew;
            if (!LAST) {
#pragma unroll
                for (int r = 0; r < 4; ++r)
                    hT[(prow + r) * 40 + uh * 16 + l15] = (short)f2bf((&hv.x)[r]);
            } else {
                *(float4*)(h_fin + (size_t)u * NPATHS + p0 + prow) = hv;
            }
        }
    }

    if (!LAST) {
        // coalesced write of block's h slice: h_outp[p0+row][ut*32 .. +32]
        __syncthreads();
#pragma unroll
        for (int i = 0; i < 2; ++i) {
            int cid = i * 256 + tid;      // 0..511
            int row = cid >> 2, seg = cid & 3;
            short8v v = *(const short8v*)(&hT[row * 40 + seg * 8]);
            *(short8v*)(h_outp + (size_t)(p0 + row) * HID + ut * 32 + seg * 8) = v;
        }
    } else {
        // per-path max over this block's 32 units -> global atomicMax (encoded)
#pragma unroll
        for (int j = 0; j < 8; ++j) {
            float m = pmax[j];
            m = fmaxf(m, __shfl_xor(m, 1, 64));
            m = fmaxf(m, __shfl_xor(m, 2, 64));
            m = fmaxf(m, __shfl_xor(m, 4, 64));
            m = fmaxf(m, __shfl_xor(m, 8, 64));
            if (l15 == 0) {
                int rt = j >> 2, r = j & 3;
                int p = p0 + wave * 32 + rt * 16 + quad * 4 + r;
                atomicMax(&logits_enc[p], encf(m));
            }
        }
    }
}

// ---------------------------------------------------------------------------
// K3: softmax over 4096 encoded logits -> normalized path weights pw[4096]
// ---------------------------------------------------------------------------
__global__ void softmax_kernel(const unsigned int* __restrict__ enc,
                               float* __restrict__ pw) {
    __shared__ float red[256];
    int tid = threadIdx.x;
    float vals[16];
    float m = -1e30f;
#pragma unroll
    for (int i = 0; i < 16; ++i) {
        unsigned int u = enc[i * 256 + tid];
        float f = (u & 0x80000000u) ? __uint_as_float(u ^ 0x80000000u)
                                    : __uint_as_float(~u);
        vals[i] = f;
        m = fmaxf(m, f);
    }
    red[tid] = m; __syncthreads();
    for (int s = 128; s > 0; s >>= 1) {
        if (tid < s) red[tid] = fmaxf(red[tid], red[tid + s]);
        __syncthreads();
    }
    m = red[0]; __syncthreads();
    float e[16];
    float sum = 0.0f;
#pragma unroll
    for (int i = 0; i < 16; ++i) { e[i] = __expf(vals[i] - m); sum += e[i]; }
    red[tid] = sum; __syncthreads();
    for (int s = 128; s > 0; s >>= 1) {
        if (tid < s) red[tid] += red[tid + s];
        __syncthreads();
    }
    float invZ = 1.0f / red[0];
#pragma unroll
    for (int i = 0; i < 16; ++i) pw[i * 256 + tid] = e[i] * invZ;
}

// ---------------------------------------------------------------------------
// K4: path_emb[u] = sum_p pw[p] * h_fin[u][p]   (block per unit, no atomics)
// ---------------------------------------------------------------------------
__global__ void attn_kernel(const float* __restrict__ h_fin,
                            const float* __restrict__ pw,
                            float* __restrict__ path_emb) {
    __shared__ float red[256];
    int u = blockIdx.x, tid = threadIdx.x;
    const float* row = h_fin + (size_t)u * NPATHS;
    float acc = 0.0f;
    for (int p = tid; p < NPATHS; p += 256) acc += pw[p] * row[p];
    red[tid] = acc; __syncthreads();
    for (int s = 128; s > 0; s >>= 1) {
        if (tid < s) red[tid] += red[tid + s];
        __syncthreads();
    }
    if (tid == 0) path_emb[u] = red[0];
}

// ---------------------------------------------------------------------------
// K5: out = sigmoid([user|item|path_emb] . w_lin + b_lin)
// ---------------------------------------------------------------------------
__global__ void final_kernel(const float* __restrict__ embedding,
                             const int* __restrict__ user_id,
                             const int* __restrict__ item_id,
                             const float* __restrict__ w_lin,
                             const float* __restrict__ b_lin,
                             const float* __restrict__ path_emb,
                             float* __restrict__ out) {
    __shared__ float red[256];
    int tid = threadIdx.x;
    int u  = user_id[0];
    int it = item_id[0];
    float s = w_lin[tid]       * embedding[(size_t)u  * DIM + tid]
            + w_lin[256 + tid] * embedding[(size_t)it * DIM + tid]
            + w_lin[512 + tid] * path_emb[tid];
    red[tid] = s; __syncthreads();
    for (int st = 128; st > 0; st >>= 1) {
        if (tid < st) red[tid] += red[tid + st];
        __syncthreads();
    }
    if (tid == 0) out[0] = 1.0f / (1.0f + __expf(-(red[0] + b_lin[0])));
}

// ---------------------------------------------------------------------------
extern "C" void kernel_launch(void* const* d_in, const int* in_sizes, int n_in,
                              void* d_out, int out_size, void* d_ws, size_t ws_size,
                              hipStream_t stream) {
    const float* embedding = (const float*)d_in[0];
    const float* w_ih      = (const float*)d_in[1];
    const float* w_hh      = (const float*)d_in[2];
    const float* b_ih      = (const float*)d_in[3];
    const float* b_hh      = (const float*)d_in[4];
    const float* w_lin     = (const float*)d_in[5];
    const float* b_lin     = (const float*)d_in[6];
    const int*   paths     = (const int*)d_in[7];
    const int*   user_id   = (const int*)d_in[8];
    const int*   item_id   = (const int*)d_in[9];
    float* outp = (float*)d_out;

    // workspace layout (~29.3 MB), 256-B aligned chunks
    char* ws = (char*)d_ws;
    size_t off = 0;
    auto alloc = [&](size_t n) { void* p = ws + off; off = (off + n + 255) & ~(size_t)255; return p; };
    unsigned short* Wc        = (unsigned short*)alloc(NGATE * KDIM * 2);        // 1 MB
    float*          bias      = (float*)alloc(NGATE * 4);                        // 4 KB
    unsigned int*   logits_enc= (unsigned int*)alloc(NPATHS * 4);                // 16 KB
    float*          pw        = (float*)alloc(NPATHS * 4);                       // 16 KB
    float*          path_emb  = (float*)alloc(HID * 4);                          // 1 KB
    unsigned short* Xb        = (unsigned short*)alloc((size_t)LPATH * NPATHS * DIM * 2); // 16 MB
    unsigned short* h_buf     = (unsigned short*)alloc((size_t)2 * NPATHS * HID * 2);     // 4 MB
    float*          c_g       = (float*)alloc((size_t)HID * NPATHS * 4);         // 4 MB
    float*          h_fin     = (float*)alloc((size_t)HID * NPATHS * 4);         // 4 MB

    prep_kernel<<<512, 256, 0, stream>>>(w_ih, w_hh, b_ih, b_hh, Wc, bias, logits_enc);
    gather_kernel<<<8192, 256, 0, stream>>>(embedding, paths, Xb);

    for (int t = 0; t < LPATH; ++t) {
        const unsigned short* hin = h_buf + (size_t)(t & 1) * NPATHS * HID;
        unsigned short*      hout = h_buf + (size_t)((t + 1) & 1) * NPATHS * HID;
        if (t == 0)
            step_kernel<true, false><<<256, 256, 0, stream>>>(Xb, Wc, bias, hin, hout,
                                                              c_g, h_fin, logits_enc, t);
        else if (t == LPATH - 1)
            step_kernel<false, true><<<256, 256, 0, stream>>>(Xb, Wc, bias, hin, hout,
                                                              c_g, h_fin, logits_enc, t);
        else
            step_kernel<false, false><<<256, 256, 0, stream>>>(Xb, Wc, bias, hin, hout,
                                                               c_g, h_fin, logits_enc, t);
    }

    softmax_kernel<<<1, 256, 0, stream>>>(logits_enc, pw);
    attn_kernel<<<HID, 256, 0, stream>>>(h_fin, pw, path_emb);
    final_kernel<<<1, 256, 0, stream>>>(embedding, user_id, item_id, w_lin, b_lin,
                                        path_emb, outp);
}

// Round 6
// 276.433 us; speedup vs baseline: 2.7109x; 1.0262x over previous
//
#include <hip/hip_runtime.h>
#include <stdint.h>

#define NPATHS 4096
#define LPATH  8
#define DIM    256
#define HID    256

typedef short  short4v __attribute__((ext_vector_type(4)));
typedef short  short8v __attribute__((ext_vector_type(8)));
typedef float  float4v __attribute__((ext_vector_type(4)));

__device__ __forceinline__ unsigned short f2bf(float f) {
    union { float f; uint32_t u; } v; v.f = f;
    uint32_t u = v.u;
    u += 0x7FFFu + ((u >> 16) & 1u);   // round-to-nearest-even
    return (unsigned short)(u >> 16);
}
__device__ __forceinline__ float bf2f(unsigned short s) {
    return __uint_as_float(((uint32_t)s) << 16);
}
__device__ __forceinline__ float fast_sigmoid(float x) {
    return 1.0f / (1.0f + __expf(-x));
}
__device__ __forceinline__ float fast_tanh(float x) {
    x = fminf(15.0f, fmaxf(-15.0f, x));
    float e = __expf(2.0f * x);
    return (e - 1.0f) / (e + 1.0f);
}
// monotone float<->uint encoding for atomicMax over signed floats
__device__ __forceinline__ unsigned int encf(float f) {
    unsigned int u = __float_as_uint(f);
    return (u & 0x80000000u) ? ~u : (u | 0x80000000u);
}
__device__ __forceinline__ float decf(unsigned int u) {
    return (u & 0x80000000u) ? __uint_as_float(u & 0x7FFFFFFFu) : __uint_as_float(~u);
}

// async global->LDS DMA, 16 B/lane (global_load_lds_dwordx4).
// LDS dest must be wave-uniform base; HW scatters lane i at base + i*16.
__device__ __forceinline__ void dma16(void* lds, const void* g) {
    typedef const unsigned int __attribute__((address_space(1)))* gp_t;
    typedef unsigned int __attribute__((address_space(3)))* lp_t;
    gp_t gp = reinterpret_cast<gp_t>(reinterpret_cast<uintptr_t>(g));
    lp_t lp = reinterpret_cast<lp_t>(static_cast<unsigned int>(reinterpret_cast<uintptr_t>(lds)));
    __builtin_amdgcn_global_load_lds(gp, lp, 16, 0, 0);
}

// ---------------------------------------------------------------------------
// K0 (combined): blocks 0..511 pack weights into B-fragment order + bias +
// zero logits/path_emb; blocks 512..8703 gather+convert embeddings to Xb.
// WfB layout (shorts): [(g*16+kc)][unit][quad*8+j]  (32 shorts per unit) so a
// step-kernel wave's load for fixed (g,kc) is one contiguous, coalesced 1 KB.
// ---------------------------------------------------------------------------
__global__ void prep_gather(const float* __restrict__ w_ih, const float* __restrict__ w_hh,
                            const float* __restrict__ b_ih, const float* __restrict__ b_hh,
                            const float* __restrict__ embedding, const int* __restrict__ paths,
                            unsigned short* __restrict__ WfB, float* __restrict__ bias,
                            unsigned int* __restrict__ logits_enc, float* __restrict__ path_emb,
                            unsigned short* __restrict__ Xb) {
    int bid = blockIdx.x;
    if (bid < 512) {
        int gid  = bid * 256 + threadIdx.x;    // 0..131071
        int base = gid * 4;                    // short index, %4==0
        int j0   = base & 31;                  // quad*8+j
        int unit = (base >> 5) & 255;
        int gkc  = base >> 13;                 // g*16+kc, 0..63
        int g    = gkc >> 4, kc = gkc & 15;
        int row  = g * 256 + unit;
        int k    = kc * 32 + j0;
        const float* src = (k < DIM) ? (w_ih + (size_t)row * DIM + k)
                                     : (w_hh + (size_t)row * HID + (k - DIM));
        float4 v = *(const float4*)src;
        short4v pk = {(short)f2bf(v.x), (short)f2bf(v.y), (short)f2bf(v.z), (short)f2bf(v.w)};
        *(short4v*)(WfB + base) = pk;
        if (gid < 1024) bias[gid] = b_ih[gid] + b_hh[gid];
        if (gid < NPATHS) logits_enc[gid] = 0u;
        if (gid < 256) path_emb[gid] = 0.0f;
    } else {
        int gid  = (bid - 512) * 256 + threadIdx.x;  // 0..2097151
        int rowt = gid >> 6;                         // t*4096 + p
        int seg  = gid & 63;
        int p    = rowt & (NPATHS - 1);
        int t    = rowt >> 12;
        int node = paths[p * LPATH + t];
        float4 v = *(const float4*)(embedding + (size_t)node * DIM + seg * 4);
        short4v pk = {(short)f2bf(v.x), (short)f2bf(v.y), (short)f2bf(v.z), (short)f2bf(v.w)};
        *(short4v*)(Xb + (size_t)rowt * DIM + seg * 4) = pk;
    }
}

// ---------------------------------------------------------------------------
// K1..K8: one LSTM step. 256 blocks x 256 threads, 64 KB static LDS.
// Block = (ptile 0..63, utile 0..3): paths p0..p0+63, units u0..u0+63.
//   blk = utile*64 + ptile => blk%8 = ptile%8 (a ptile's 4 blocks share XCD).
// Wave w: 16 units (u0+w*16+l15), all 4 gates, all 64 path rows.
//   B: 4 gates x 16 kc x short8 = 256 VGPRs, loaded coalesced from WfB.
//   i,f,g,o of one (path,unit) land in the SAME lane -> register pointwise.
// sA = 64x512 [x_t|h] tile in MFMA-fragment order [frag][lane][16B]:
//   one dma16 per frag (wave-uniform dest), ONE barrier, then 16 kc iters of
//   conflict-free ds_read_b128.  c: global fp32 [path][unit].
// ---------------------------------------------------------------------------
template<bool FIRST, bool LAST>
__global__ __launch_bounds__(256, 1)
void step_kernel(const unsigned short* __restrict__ Xb,     // [8][4096][256]
                 const unsigned short* __restrict__ WfB,    // frag-ordered
                 const float* __restrict__ bias,            // [1024]
                 const unsigned short* __restrict__ h_in,   // [4096][256] bf16
                 unsigned short* __restrict__ h_out,        // [4096][256] bf16
                 float* __restrict__ c_g,                   // [4096][256] fp32
                 unsigned int* __restrict__ logits_enc,     // [4096] (LAST)
                 int t) {
    __shared__ __align__(16) short sA[64 * 512];   // 64 frags x 64 lanes x 8 shorts

    const int tid   = threadIdx.x;
    const int wave  = tid >> 6;
    const int lane  = tid & 63;
    const int l15   = lane & 15;
    const int quad  = lane >> 4;
    const int blk   = blockIdx.x;
    const int ptile = blk & 63;
    const int utile = blk >> 6;
    const int p0    = ptile * 64;
    const int u0    = utile * 64;

    // ---- A staging: 16 dma16/thread in fragment order ----
    {
        const char* xpl = (const char*)Xb + ((size_t)t * NPATHS + p0) * 512;
        const char* hpl = (const char*)h_in + (size_t)p0 * 512;
        const char* xl  = xpl + l15 * 512 + quad * 16;
        const char* hl  = hpl + l15 * 512 + quad * 16;
#pragma unroll
        for (int m = 0; m < 16; ++m) {
            int rf = m >> 2, kq = m & 3;
            if (FIRST && kq >= 2) continue;          // h==0 at t=0
            int fp = rf * 16 + kq * 4 + wave;        // frag id, wave-uniform
            const char* base = (kq < 2) ? xl : hl;
            int kk = ((kq & 1) * 4 + wave) * 64;     // (kc&7)*64 bytes in row
            dma16(sA + fp * 512, base + rf * 8192 + kk);
        }
    }

    // ---- B fragments + bias (registers, coalesced loads; overlap w/ DMA) ----
    short8v Bf[4][16];
    float bb[4];
    const int unit = u0 + wave * 16 + l15;
#pragma unroll
    for (int g = 0; g < 4; ++g) {
        bb[g] = bias[g * 256 + unit];
#pragma unroll
        for (int kc = 0; kc < 16; ++kc)
            Bf[g][kc] = *(const short8v*)(WfB + (((g * 16 + kc) * 256 + unit) * 32 + quad * 8));
    }

    __syncthreads();   // single vmcnt drain: tile resident

    // ---- MFMA: 64 paths x 256 gate-cols, K=512 (256 at t=0) ----
    float4v acc[4][4];
    const float4v z4 = {0.0f, 0.0f, 0.0f, 0.0f};
#pragma unroll
    for (int rf = 0; rf < 4; ++rf)
#pragma unroll
        for (int g = 0; g < 4; ++g) acc[rf][g] = z4;

    auto kstep = [&](int kc) {
#pragma unroll
        for (int rf = 0; rf < 4; ++rf) {
            short8v a = *(const short8v*)(sA + ((rf * 16 + kc) << 9) + lane * 8);
#pragma unroll
            for (int g = 0; g < 4; ++g)
                acc[rf][g] = __builtin_amdgcn_mfma_f32_16x16x32_bf16(
                    a, Bf[g][kc], acc[rf][g], 0, 0, 0);
        }
    };
    if (FIRST) {
#pragma unroll
        for (int kc = 0; kc < 8; ++kc) kstep(kc);
    } else {
#pragma unroll
        for (int kc = 0; kc < 16; ++kc) kstep(kc);
    }

    // ---- pointwise LSTM update (i,f,g,o same-lane) ----
    float hmax[16];
#pragma unroll
    for (int rf = 0; rf < 4; ++rf) {
#pragma unroll
        for (int r = 0; r < 4; ++r) {
            int row = rf * 16 + quad * 4 + r;       // block-local path row
            int idx = rf * 4 + r;
            float iv = acc[rf][0][r] + bb[0];
            float fv = acc[rf][1][r] + bb[1];
            float gv = acc[rf][2][r] + bb[2];
            float ov = acc[rf][3][r] + bb[3];
            size_t coff = (size_t)(p0 + row) * HID + unit;
            float cp = FIRST ? 0.0f : c_g[coff];
            float cn = fast_sigmoid(fv) * cp + fast_sigmoid(iv) * fast_tanh(gv);
            if (!LAST) c_g[coff] = cn;
            float h = fast_sigmoid(ov) * fast_tanh(cn);
            hmax[idx] = h;
            h_out[(size_t)(p0 + row) * HID + unit] = f2bf(h);
        }
    }

    if (LAST) {
        // per-path max over this wave's 16 units -> atomicMax (encoded)
#pragma unroll
        for (int idx = 0; idx < 16; ++idx) {
            float m = hmax[idx];
            m = fmaxf(m, __shfl_xor(m, 1, 64));
            m = fmaxf(m, __shfl_xor(m, 2, 64));
            m = fmaxf(m, __shfl_xor(m, 4, 64));
            m = fmaxf(m, __shfl_xor(m, 8, 64));
            if (l15 == 0) {
                int rf = idx >> 2, r = idx & 3;
                atomicMax(&logits_enc[p0 + rf * 16 + quad * 4 + r], encf(m));
            }
        }
    }
}

// ---------------------------------------------------------------------------
// K9: softmax scalars over 4096 encoded logits -> scal = {max, 1/Z}
// ---------------------------------------------------------------------------
__global__ void softmax_prep_kernel(const unsigned int* __restrict__ enc,
                                    float* __restrict__ scal) {
    __shared__ float red[256];
    int tid = threadIdx.x;
    float vals[16];
    float m = -1e30f;
#pragma unroll
    for (int i = 0; i < 16; ++i) {
        vals[i] = decf(enc[i * 256 + tid]);
        m = fmaxf(m, vals[i]);
    }
    red[tid] = m; __syncthreads();
    for (int s = 128; s > 0; s >>= 1) {
        if (tid < s) red[tid] = fmaxf(red[tid], red[tid + s]);
        __syncthreads();
    }
    m = red[0]; __syncthreads();
    float sum = 0.0f;
#pragma unroll
    for (int i = 0; i < 16; ++i) sum += __expf(vals[i] - m);
    red[tid] = sum; __syncthreads();
    for (int s = 128; s > 0; s >>= 1) {
        if (tid < s) red[tid] += red[tid + s];
        __syncthreads();
    }
    if (tid == 0) { scal[0] = m; scal[1] = 1.0f / red[0]; }
}

// ---------------------------------------------------------------------------
// K10: path_emb[u] = sum_p softmax_p * h_final[p][u]  (block partial + atomic)
// ---------------------------------------------------------------------------
__global__ void attn_sum_kernel(const unsigned short* __restrict__ h_final,
                                const unsigned int* __restrict__ enc,
                                const float* __restrict__ scal,
                                float* __restrict__ path_emb) {
    int tid = threadIdx.x;
    int p0  = blockIdx.x * 16;
    float bmax = scal[0], invZ = scal[1];
    float acc = 0.0f;
    for (int p = p0; p < p0 + 16; ++p) {
        float w = __expf(decf(enc[p]) - bmax) * invZ;
        acc += w * bf2f(h_final[(size_t)p * HID + tid]);
    }
    atomicAdd(&path_emb[tid], acc);
}

// ---------------------------------------------------------------------------
// K11: out = sigmoid([user|item|path_emb] . w_lin + b_lin)
// ---------------------------------------------------------------------------
__global__ void final_kernel(const float* __restrict__ embedding,
                             const int* __restrict__ user_id,
                             const int* __restrict__ item_id,
                             const float* __restrict__ w_lin,
                             const float* __restrict__ b_lin,
                             const float* __restrict__ path_emb,
                             float* __restrict__ out) {
    __shared__ float red[256];
    int tid = threadIdx.x;
    int u  = user_id[0];
    int it = item_id[0];
    float s = w_lin[tid]       * embedding[(size_t)u  * DIM + tid]
            + w_lin[256 + tid] * embedding[(size_t)it * DIM + tid]
            + w_lin[512 + tid] * path_emb[tid];
    red[tid] = s; __syncthreads();
    for (int st = 128; st > 0; st >>= 1) {
        if (tid < st) red[tid] += red[tid + st];
        __syncthreads();
    }
    if (tid == 0) out[0] = 1.0f / (1.0f + __expf(-(red[0] + b_lin[0])));
}

// ---------------------------------------------------------------------------
extern "C" void kernel_launch(void* const* d_in, const int* in_sizes, int n_in,
                              void* d_out, int out_size, void* d_ws, size_t ws_size,
                              hipStream_t stream) {
    const float* embedding = (const float*)d_in[0];
    const float* w_ih      = (const float*)d_in[1];
    const float* w_hh      = (const float*)d_in[2];
    const float* b_ih      = (const float*)d_in[3];
    const float* b_hh      = (const float*)d_in[4];
    const float* w_lin     = (const float*)d_in[5];
    const float* b_lin     = (const float*)d_in[6];
    const int*   paths     = (const int*)d_in[7];
    const int*   user_id   = (const int*)d_in[8];
    const int*   item_id   = (const int*)d_in[9];
    float* outp = (float*)d_out;

    // workspace layout (~25.1 MB), 256-B aligned
    char* ws = (char*)d_ws;
    size_t off = 0;
    auto alloc = [&](size_t n) { void* p = ws + off; off = (off + n + 255) & ~(size_t)255; return p; };
    unsigned short* WfB       = (unsigned short*)alloc((size_t)1024 * 512 * 2);           // 1 MB
    float*          bias      = (float*)alloc(1024 * 4);                                  // 4 KB
    unsigned int*   logits_enc= (unsigned int*)alloc(NPATHS * 4);                         // 16 KB
    float*          scal      = (float*)alloc(256);                                       // 2 used
    float*          path_emb  = (float*)alloc(HID * 4);                                   // 1 KB
    unsigned short* Xb        = (unsigned short*)alloc((size_t)LPATH * NPATHS * DIM * 2); // 16 MB
    unsigned short* h_buf     = (unsigned short*)alloc((size_t)2 * NPATHS * HID * 2);     // 4 MB
    float*          c_g       = (float*)alloc((size_t)NPATHS * HID * 4);                  // 4 MB

    prep_gather<<<8704, 256, 0, stream>>>(w_ih, w_hh, b_ih, b_hh, embedding, paths,
                                          WfB, bias, logits_enc, path_emb, Xb);

    for (int t = 0; t < LPATH; ++t) {
        const unsigned short* hin = h_buf + (size_t)(t & 1) * NPATHS * HID;
        unsigned short*      hout = h_buf + (size_t)((t + 1) & 1) * NPATHS * HID;
        if (t == 0)
            step_kernel<true, false><<<256, 256, 0, stream>>>(Xb, WfB, bias, hin, hout,
                                                              c_g, logits_enc, t);
        else if (t == LPATH - 1)
            step_kernel<false, true><<<256, 256, 0, stream>>>(Xb, WfB, bias, hin, hout,
                                                              c_g, logits_enc, t);
        else
            step_kernel<false, false><<<256, 256, 0, stream>>>(Xb, WfB, bias, hin, hout,
                                                               c_g, logits_enc, t);
    }

    // final h is in h_buf plane 0 (8 steps of ping-pong)
    softmax_prep_kernel<<<1, 256, 0, stream>>>(logits_enc, scal);
    attn_sum_kernel<<<NPATHS / 16, 256, 0, stream>>>(h_buf, logits_enc, scal, path_emb);
    final_kernel<<<1, 256, 0, stream>>>(embedding, user_id, item_id, w_lin, b_lin,
                                        path_emb, outp);
}